// Round 9
// baseline (123.320 us; speedup 1.0000x reference)
//
#include <hip/hip_runtime.h>
#include <math.h>

// Problem constants (from reference setup_inputs)
constexpr int B = 16, N = 1024, Cin = 64, C = 64, K = 3;
constexpr int BN = B * N;
constexpr int GRID = 512;          // 32 blocks per batch, co-resident (proven r5-r8)
constexpr int ROWS = 32;           // n-rows per block
#define LN_EPS 1e-5f

// ---------------------------------------------------------------------------
// Per-batch barrier (32 blocks) on a private 128B line. Proven r7.
//  - __syncthreads() drains vmcnt(0) first -> this block's agent-scope
//    write-through stores are globally visible before the RELAXED add.
//  - No buffer_wbl2 / buffer_inv cache ops at all.
//  - Bounded spin: fail-wrong instead of hang if co-residency ever breaks.
// ---------------------------------------------------------------------------
__device__ __forceinline__ void bbar(unsigned int* cnt) {
    __syncthreads();
    if (threadIdx.x == 0) {
        __hip_atomic_fetch_add(cnt, 1u, __ATOMIC_RELAXED, __HIP_MEMORY_SCOPE_AGENT);
        int spins = 0;
        while (__hip_atomic_load(cnt, __ATOMIC_RELAXED, __HIP_MEMORY_SCOPE_AGENT) < 32u) {
            __builtin_amdgcn_s_sleep(8);                 // ~0.2 us backoff
            if (++spins > (1 << 17)) break;              // bail, no hang
        }
    }
    __syncthreads();
}

// ---------------------------------------------------------------------------
// Persistent kernel, 512 blocks x 256. Block (b = blk/32, rbase = (blk%32)*32)
// owns 32 n-rows of batch b FOR ALL THREE PASSES, holding its 128 KB A-tile
// in VGPRs (float4 Ar[2][4][4] = 128 VGPRs/thread).
// __launch_bounds__(256, 2): 2 waves/EU min -> 256-VGPR budget. Without this
// the allocator targeted ~6 waves/EU (84 VGPRs, round 8) and SANK the A loads
// back into the pass loop, re-reading A 3x. We only run 2 blocks/CU, so
// occupancy beyond 2 waves/EU is worthless -- spend the registers.
//  Phase 0: A->regs + P0 rows = X.sum(-1) + hl = h^T slice   | bbar
//  Pass 1:  P1 rows = A @ P0   (pure VALU, x from LDS)       | bbar
//  Pass 2:  P2 rows = A @ P1                                 | bbar
//  Pass 3:  P3 rows (LDS only) + taps + LayerNorm + tanh
// ---------------------------------------------------------------------------
__global__ void __launch_bounds__(256, 2)
fused_persist(const float* __restrict__ A, const float* __restrict__ X,
              const float* __restrict__ h, const float* __restrict__ gamma,
              const float* __restrict__ beta, float* __restrict__ out,
              unsigned int* __restrict__ bar, float* __restrict__ P) {
    __shared__ float hl[K + 1][ROWS][C];            // 32 KB: hl[i][nn][c] = h[i][c][rbase+nn]
    __shared__ __align__(16) float4 xs[N / 4];      // 4 KB: current x-vector
    __shared__ float p3s[ROWS];
    const int tid   = threadIdx.x;
    const int lane  = tid & 63;
    const int w     = tid >> 6;                     // wave 0..3
    const int b     = blockIdx.x >> 5;              // batch
    const int rbase = (blockIdx.x & 31) * ROWS;     // this block's rows
    unsigned int* mybar = bar + (size_t)b * 3 * 32; // 3 private lines per batch

    // ---- Phase 0a: issue the A-row loads into registers FIRST -------------
    // Lane's slice of row (rbase + r*16 + w*4 + j): float4 at idx k*64+lane.
    const float* Ab = A + ((size_t)b << 20);
    float4 Ar[2][4][4];
    #pragma unroll
    for (int r = 0; r < 2; ++r)
        #pragma unroll
        for (int j = 0; j < 4; ++j) {
            const float4* rp = (const float4*)(Ab + (size_t)(rbase + r * 16 + w * 4 + j) * N);
            #pragma unroll
            for (int k = 0; k < 4; ++k)
                Ar[r][j][k] = rp[k * 64 + lane];    // coalesced: lane-consecutive float4
        }

    // ---- Phase 0b: P0 for our rows (wave w: 8 n's, lane = c) --------------
    {
        const float* Xb = X + ((size_t)b * N + rbase) * Cin;
        float* P0 = P + (size_t)b * N;
        #pragma unroll
        for (int j = 0; j < 8; ++j) {
            int nn = w * 8 + j;
            float v = Xb[(size_t)nn * Cin + lane];
            #pragma unroll
            for (int off = 32; off; off >>= 1) v += __shfl_xor(v, off);
            if (lane == 0)
                __hip_atomic_store(&P0[rbase + nn], v, __ATOMIC_RELAXED,
                                   __HIP_MEMORY_SCOPE_AGENT);
        }
    }

    // ---- Phase 0c: hl[i][nn][c] = h[i][c][rbase+nn] (thread = (i,c)) ------
    {
        const float* src = h + ((size_t)w * C + lane) * N + rbase;  // i = w, c = lane
        #pragma unroll
        for (int j4 = 0; j4 < 8; ++j4) {
            float4 v = ((const float4*)src)[j4];
            hl[w][j4 * 4 + 0][lane] = v.x;
            hl[w][j4 * 4 + 1][lane] = v.y;
            hl[w][j4 * 4 + 2][lane] = v.z;
            hl[w][j4 * 4 + 3][lane] = v.w;
        }
    }
    bbar(mybar);                                    // P0[b] complete

    // ---- Passes 1..3: matvec chain, A entirely from registers -------------
    for (int it = 0; it < 3; ++it) {
        const float* xsrc = P + (size_t)it * BN + (size_t)b * N;
        xs[tid] = ((const float4*)xsrc)[tid];       // fresh: first touch after bbar
        __syncthreads();

        float acc[2][4] = {{0.f, 0.f, 0.f, 0.f}, {0.f, 0.f, 0.f, 0.f}};
        #pragma unroll
        for (int k = 0; k < 4; ++k) {
            float4 xx = xs[k * 64 + lane];          // one ds_read_b128, reused 8x
            #pragma unroll
            for (int r = 0; r < 2; ++r)
                #pragma unroll
                for (int j = 0; j < 4; ++j) {
                    float4 a = Ar[r][j][k];
                    acc[r][j] += a.x * xx.x + a.y * xx.y + a.z * xx.z + a.w * xx.w;
                }
        }
        #pragma unroll
        for (int off = 32; off; off >>= 1)
            #pragma unroll
            for (int r = 0; r < 2; ++r)
                #pragma unroll
                for (int j = 0; j < 4; ++j)
                    acc[r][j] += __shfl_xor(acc[r][j], off);

        if (lane == 0) {
            if (it < 2) {
                float* ydst = P + (size_t)(it + 1) * BN + (size_t)b * N;
                #pragma unroll
                for (int r = 0; r < 2; ++r)
                    #pragma unroll
                    for (int j = 0; j < 4; ++j)
                        __hip_atomic_store(&ydst[rbase + r * 16 + w * 4 + j], acc[r][j],
                                           __ATOMIC_RELAXED, __HIP_MEMORY_SCOPE_AGENT);
            } else {                                // P3 stays in LDS
                #pragma unroll
                for (int r = 0; r < 2; ++r)
                    #pragma unroll
                    for (int j = 0; j < 4; ++j)
                        p3s[r * 16 + w * 4 + j] = acc[r][j];
            }
        }
        if (it < 2) bbar(mybar + (1 + it) * 32);    // publish P[it+1][b]
        else        __syncthreads();                // publish p3s block-locally
    }

    // ---- Phase 4: taps + LayerNorm + tanh (wave w: 8 n's, lane = c) -------
    const float g  = gamma[lane];
    const float be = beta[lane];
    #pragma unroll
    for (int j = 0; j < 8; ++j) {
        const int nn = w * 8 + j;
        const int n  = rbase + nn;
        float y = p3s[nn] * hl[3][nn][lane];
        #pragma unroll
        for (int i = 0; i < 3; ++i) {
            float pv = P[(size_t)i * BN + (size_t)b * N + n];   // wave-uniform, cached
            y += pv * hl[i][nn][lane];
        }
        float s = y;
        #pragma unroll
        for (int off = 32; off; off >>= 1) s += __shfl_xor(s, off);
        float mu = s * (1.0f / 64.0f);
        float d  = y - mu;
        float v  = d * d;
        #pragma unroll
        for (int off = 32; off; off >>= 1) v += __shfl_xor(v, off);
        float var = v * (1.0f / 64.0f);
        float yn  = d * rsqrtf(var + LN_EPS) * g + be;
        out[((size_t)b * N + n) * C + lane] = tanhf(yn);
    }
}

// ---------------------------------------------------------------------------
extern "C" void kernel_launch(void* const* d_in, const int* in_sizes, int n_in,
                              void* d_out, int out_size, void* d_ws, size_t ws_size,
                              hipStream_t stream) {
    const float* A     = (const float*)d_in[0];  // [B,N,N]
    const float* X     = (const float*)d_in[1];  // [B,N,Cin]
    const float* h     = (const float*)d_in[2];  // [K+1,C,N]
    const float* gamma = (const float*)d_in[3];  // [C]
    const float* beta  = (const float*)d_in[4];  // [C]
    float* out = (float*)d_out;                  // [B,N,C]

    // ws layout: barrier counters (16 batches x 3 x 32 uints = 6 KB, zeroed
    // here; ws arrives 0xAA-poisoned), then P[3][B][N] (192 KB).
    unsigned int* bar = (unsigned int*)d_ws;
    float* P = (float*)((char*)d_ws + 8192);

    hipMemsetAsync(bar, 0, B * 3 * 32 * sizeof(unsigned int), stream);
    fused_persist<<<GRID, 256, 0, stream>>>(A, X, h, gamma, beta, out, bar, P);
}

// Round 10
// 120.998 us; speedup vs baseline: 1.0192x; 1.0192x over previous
//
#include <hip/hip_runtime.h>
#include <math.h>

// Problem constants (from reference setup_inputs)
constexpr int B = 16, N = 1024, Cin = 64, C = 64, K = 3;
constexpr int BN = B * N;
constexpr int GRID = 512;          // 32 blocks per batch, 2 blocks/CU co-resident
constexpr int ROWS = 32;           // n-rows per block
#define LN_EPS 1e-5f

// ---------------------------------------------------------------------------
// Per-batch barrier (32 blocks) on a private 128B line. Proven r7-r9.
// ---------------------------------------------------------------------------
__device__ __forceinline__ void bbar(unsigned int* cnt) {
    __syncthreads();
    if (threadIdx.x == 0) {
        __hip_atomic_fetch_add(cnt, 1u, __ATOMIC_RELAXED, __HIP_MEMORY_SCOPE_AGENT);
        int spins = 0;
        while (__hip_atomic_load(cnt, __ATOMIC_RELAXED, __HIP_MEMORY_SCOPE_AGENT) < 32u) {
            __builtin_amdgcn_s_sleep(8);
            if (++spins > (1 << 17)) break;              // bail, no hang
        }
    }
    __syncthreads();
}

// ---------------------------------------------------------------------------
// Persistent kernel, 512 blocks x 256. Block (b = blk/32, rbase = (blk%32)*32)
// owns 32 n-rows of batch b for all three passes. The 128 KB A-tile lives
// ON-CHIP for the whole kernel:
//   rows rbase+ 0..15 -> LDS  As[16][1024]          (64 KB, staged once)
//   rows rbase+16..31 -> VGPR Ar[4][4] per thread   (64 regs, asm-pinned)
// The asm volatile "+v" on every Ar component makes the values asm-defined,
// so the allocator CANNOT rematerialize the global loads inside the pass
// loop (rounds 8/9: plain register arrays got re-loaded 3x, VGPR_Count=84).
// u.As is dead after pass 3 and is aliased with the phase-4 hl buffer.
//  Phase 0: A->LDS+regs, P0 rows = X.sum(-1)        | bbar
//  Pass 1:  P1 = A @ P0  (LDS half + reg half)      | bbar
//  Pass 2:  P2 = A @ P1                             | bbar
//  Pass 3:  P3 (stays in LDS)                       | syncthreads
//  Phase 4: hl = h^T slice (coalesced), taps + LayerNorm + tanh
// ---------------------------------------------------------------------------
__global__ void __launch_bounds__(256, 2)
fused_persist(const float* __restrict__ A, const float* __restrict__ X,
              const float* __restrict__ h, const float* __restrict__ gamma,
              const float* __restrict__ beta, float* __restrict__ out,
              unsigned int* __restrict__ bar, float* __restrict__ P) {
    __shared__ __align__(16) union SU {
        float As[16][1024];            // 64 KB: A rows rbase+0..15 (passes 1-3)
        float hl[K + 1][ROWS][65];     // 33 KB: h^T slice (phase 4 only)
    } u;
    __shared__ __align__(16) float4 xs[N / 4];      // 4 KB: current x-vector
    __shared__ float p3s[ROWS];
    const int tid   = threadIdx.x;
    const int lane  = tid & 63;
    const int w     = tid >> 6;                     // wave 0..3
    const int b     = blockIdx.x >> 5;              // batch
    const int rbase = (blockIdx.x & 31) * ROWS;     // this block's rows
    unsigned int* mybar = bar + (size_t)b * 3 * 32; // 3 private lines per batch
    const float* Ab = A + ((size_t)b << 20);

    // ---- Phase 0a: A-tile -> registers (rows rbase+16 + w*4 + j) ----------
    float4 Ar[4][4];
    #pragma unroll
    for (int j = 0; j < 4; ++j) {
        const float4* rp = (const float4*)(Ab + (size_t)(rbase + 16 + w * 4 + j) * N);
        #pragma unroll
        for (int k = 0; k < 4; ++k)
            Ar[j][k] = rp[k * 64 + lane];           // coalesced 1 KB/instr
    }
    // Pin: asm-defined values cannot be rematerialized -> loads stay hoisted.
    #pragma unroll
    for (int j = 0; j < 4; ++j)
        #pragma unroll
        for (int k = 0; k < 4; ++k)
            asm volatile("" : "+v"(Ar[j][k].x), "+v"(Ar[j][k].y),
                              "+v"(Ar[j][k].z), "+v"(Ar[j][k].w));

    // ---- Phase 0b: A-tile rows rbase+0..15 -> LDS (cooperative) -----------
    #pragma unroll
    for (int i = 0; i < 16; ++i) {                  // 4096 float4s / 256 threads
        int idx  = i * 256 + tid;
        int row  = idx >> 8;                        // 0..15
        int col4 = idx & 255;
        ((float4*)u.As[row])[col4] =
            ((const float4*)(Ab + (size_t)(rbase + row) * N))[col4];
    }

    // ---- Phase 0c: P0 for our rows (wave w: 8 n's, lane = c) --------------
    {
        const float* Xb = X + ((size_t)b * N + rbase) * Cin;
        float* P0 = P + (size_t)b * N;
        #pragma unroll
        for (int j = 0; j < 8; ++j) {
            int nn = w * 8 + j;
            float v = Xb[(size_t)nn * Cin + lane];
            #pragma unroll
            for (int off = 32; off; off >>= 1) v += __shfl_xor(v, off);
            if (lane == 0)
                __hip_atomic_store(&P0[rbase + nn], v, __ATOMIC_RELAXED,
                                   __HIP_MEMORY_SCOPE_AGENT);
        }
    }
    bbar(mybar);                                    // P0[b] complete (As also done)

    // ---- Passes 1..3: matvec, A entirely on-chip --------------------------
    for (int it = 0; it < 3; ++it) {
        const float* xsrc = P + (size_t)it * BN + (size_t)b * N;
        xs[tid] = ((const float4*)xsrc)[tid];       // fresh: first touch after bbar
        __syncthreads();

        float accL[4] = {0.f, 0.f, 0.f, 0.f};      // LDS rows  rbase + w*4 + j
        float accR[4] = {0.f, 0.f, 0.f, 0.f};      // reg rows  rbase + 16 + w*4 + j
        #pragma unroll
        for (int k = 0; k < 4; ++k) {
            float4 xx = xs[k * 64 + lane];
            #pragma unroll
            for (int j = 0; j < 4; ++j) {
                float4 aL = ((const float4*)u.As[w * 4 + j])[k * 64 + lane];
                accL[j] += aL.x * xx.x + aL.y * xx.y + aL.z * xx.z + aL.w * xx.w;
                float4 aR = Ar[j][k];
                accR[j] += aR.x * xx.x + aR.y * xx.y + aR.z * xx.z + aR.w * xx.w;
            }
        }
        #pragma unroll
        for (int off = 32; off; off >>= 1)
            #pragma unroll
            for (int j = 0; j < 4; ++j) {
                accL[j] += __shfl_xor(accL[j], off);
                accR[j] += __shfl_xor(accR[j], off);
            }

        if (lane == 0) {
            if (it < 2) {
                float* ydst = P + (size_t)(it + 1) * BN + (size_t)b * N + rbase;
                #pragma unroll
                for (int j = 0; j < 4; ++j) {
                    __hip_atomic_store(&ydst[w * 4 + j],      accL[j],
                                       __ATOMIC_RELAXED, __HIP_MEMORY_SCOPE_AGENT);
                    __hip_atomic_store(&ydst[16 + w * 4 + j], accR[j],
                                       __ATOMIC_RELAXED, __HIP_MEMORY_SCOPE_AGENT);
                }
            } else {                                // P3 stays in LDS
                #pragma unroll
                for (int j = 0; j < 4; ++j) {
                    p3s[w * 4 + j]      = accL[j];
                    p3s[16 + w * 4 + j] = accR[j];
                }
            }
        }
        if (it < 2) bbar(mybar + (1 + it) * 32);    // publish P[it+1][b]
        else        __syncthreads();                // p3s visible; As now dead
    }

    // ---- Phase 4a: hl[i][nn][c] = h[i][c][rbase+nn], fully coalesced ------
    // lane -> (cofs = lane>>3, nngrp = lane&7): every fetched line fully used.
    {
        const int i4    = tid >> 6;                 // 0..3  (= K-tap index)
        const int cofs  = (tid & 63) >> 3;          // 0..7
        const int nngrp = tid & 7;                  // 0..7
        #pragma unroll
        for (int c0 = 0; c0 < 64; c0 += 8) {
            int c = c0 + cofs;
            float4 v = *(const float4*)(h + ((size_t)i4 * C + c) * N + rbase + nngrp * 4);
            int nn0 = nngrp * 4;
            u.hl[i4][nn0 + 0][c] = v.x;
            u.hl[i4][nn0 + 1][c] = v.y;
            u.hl[i4][nn0 + 2][c] = v.z;
            u.hl[i4][nn0 + 3][c] = v.w;
        }
    }
    __syncthreads();

    // ---- Phase 4b: taps + LayerNorm + tanh (wave w: 8 n's, lane = c) ------
    const float g  = gamma[lane];
    const float be = beta[lane];
    #pragma unroll
    for (int j = 0; j < 8; ++j) {
        const int nn = w * 8 + j;
        const int n  = rbase + nn;
        float y = p3s[nn] * u.hl[3][nn][lane];
        #pragma unroll
        for (int i = 0; i < 3; ++i) {
            float pv = P[(size_t)i * BN + (size_t)b * N + n];   // wave-uniform, cached
            y += pv * u.hl[i][nn][lane];
        }
        float s = y;
        #pragma unroll
        for (int off = 32; off; off >>= 1) s += __shfl_xor(s, off);
        float mu = s * (1.0f / 64.0f);
        float d  = y - mu;
        float v  = d * d;
        #pragma unroll
        for (int off = 32; off; off >>= 1) v += __shfl_xor(v, off);
        float var = v * (1.0f / 64.0f);
        float yn  = d * rsqrtf(var + LN_EPS) * g + be;
        out[((size_t)b * N + n) * C + lane] = tanhf(yn);
    }
}

// ---------------------------------------------------------------------------
extern "C" void kernel_launch(void* const* d_in, const int* in_sizes, int n_in,
                              void* d_out, int out_size, void* d_ws, size_t ws_size,
                              hipStream_t stream) {
    const float* A     = (const float*)d_in[0];  // [B,N,N]
    const float* X     = (const float*)d_in[1];  // [B,N,Cin]
    const float* h     = (const float*)d_in[2];  // [K+1,C,N]
    const float* gamma = (const float*)d_in[3];  // [C]
    const float* beta  = (const float*)d_in[4];  // [C]
    float* out = (float*)d_out;                  // [B,N,C]

    // ws layout: barrier counters (16 batches x 3 x 32 uints = 6 KB, zeroed
    // here; ws arrives 0xAA-poisoned), then P[3][B][N] (192 KB).
    unsigned int* bar = (unsigned int*)d_ws;
    float* P = (float*)((char*)d_ws + 8192);

    hipMemsetAsync(bar, 0, B * 3 * 32 * sizeof(unsigned int), stream);
    fused_persist<<<GRID, 256, 0, stream>>>(A, X, h, gamma, beta, out, bar, P);
}